// Round 9
// baseline (148.405 us; speedup 1.0000x reference)
//
#include <hip/hip_runtime.h>

// SLAYER 2-layer SNN, MI355X. Round-9: 1024-thread blocks, 16 waves split the
// latency-bound phases (each wave: 16 LDS-gather iterations instead of 64, at
// 4 waves/SIMD for overlap). Lesson r2-r8: compiler serializes LDS gather
// chains (~240cyc each); only TLP hides it (r6 evidence). In-block ballot-free
// packing replaces KA (input is L3-resident after harness restore).
//   KB: pack 20 halo rows -> rowT LDS -> conv1 (2-row LUTs, wave=px-row)
//       -> ct LDS -> scan1 (waves 0-3, lanes=px) -> transpose -> s1h
//   KC: pack 18 w18-rows -> conv2 9-bit patterns -> scan2 (lut3[512], 1
//       gather/px.t) -> transpose -> coalesced float out
// All sums keep the associations of rounds 0-8 (absmax == 0 every round).

#define HH   192
#define WW   192
#define NIMG 4
#define TT   64
#define NT   1024
#define XH   12    // 16-bit x-halfwords per image row

#define E_D 2.718281828459045
static constexpr float D1  = (float)0.36787944117144233;   // exp(-1/1)
static constexpr float CP1 = (float)(E_D);
static constexpr float DR1 = (float)0.36787944117144233;
static constexpr float CR1 = (float)(-30.0 * E_D);
static constexpr float D2  = (float)0.6065306597126334;    // exp(-1/2)
static constexpr float CP2 = (float)(E_D * 0.5);
static constexpr float DR2 = (float)0.6065306597126334;
static constexpr float CR2 = (float)(-50.0 * E_D * 0.5);
static constexpr float TH1 = 30.0f;
static constexpr float TH2 = 50.0f;

// ---------------- KB: pack + conv1 (2-row LUTs) + scan1 -> s1h -------------
__global__ __launch_bounds__(NT, 1)
void kb_layer1(const float* __restrict__ in, const float* __restrict__ w1g,
               unsigned short* __restrict__ s1h) {
    __shared__ float    lutA[1024];       // rows 0+1: l0(p&31)+l1(p>>5)
    __shared__ float    lutB[1024];       // rows 2+3
    __shared__ float    lutC[32];         // row 4
    __shared__ unsigned rowT[20 * 64];    // packed halo rows, lane = t
    __shared__ float    ct[256 * 65];     // conv out [px][t], stride 65
    __shared__ uint2    tb[256];

    const int n = blockIdx.z, ty = blockIdx.y, tx = blockIdx.x;
    const int y0 = ty * 16, x0 = tx * 16;
    const int tid = threadIdx.x;
    const int wv = tid >> 6, ln = tid & 63;

    // LUT build: one entry per thread; j-ascending per accumulator == r8.
    {
        const int e = tid;
        float l0 = 0.f, l1 = 0.f, l2 = 0.f, l3 = 0.f;
#pragma unroll
        for (int j = 0; j < 5; j++) {
            if ((e >> j) & 1)       { l0 += w1g[j];     l2 += w1g[10 + j]; }
            if ((e >> (5 + j)) & 1) { l1 += w1g[5 + j]; l3 += w1g[15 + j]; }
        }
        lutA[e] = l0 + l1;
        lutB[e] = l2 + l3;
    }
    if (tid < 32) {
        float s = 0.f;
#pragma unroll
        for (int j = 0; j < 5; j++)
            if ((tid >> j) & 1) s += w1g[20 + j];
        lutC[tid] = s;
    }

    // Pack phase: 20 halo rows split over 16 waves; lanes = t, coalesced.
    for (int r = wv; r < 20; r += 16) {
        const int gy = y0 - 2 + r;
        unsigned word = 0u;
        if (gy >= 0 && gy < HH) {
            const float* rowp = in + ((size_t)(n * HH + gy) * WW) * TT + ln;
#pragma unroll
            for (int c = 0; c < 20; c++) {
                const int gx = x0 - 2 + c;
                if (gx >= 0 && gx < WW) {
                    const float v = rowp[(size_t)gx * TT];
                    word |= (v != 0.f) ? (1u << c) : 0u;
                }
            }
        }
        rowT[r * 64 + ln] = word;
    }
    __syncthreads();

    // Conv phase: wave wv -> px row wv; 16 gather-iterations per wave.
    {
        unsigned w20[5];
#pragma unroll
        for (int dy = 0; dy < 5; dy++) w20[dy] = rowT[(wv + dy) * 64 + ln];
#pragma unroll
        for (int col = 0; col < 16; col++) {
            const unsigned pA = ((w20[0] >> col) & 31)
                              | (((w20[1] >> col) & 31) << 5);
            const unsigned pB = ((w20[2] >> col) & 31)
                              | (((w20[3] >> col) & 31) << 5);
            const unsigned pC = (w20[4] >> col) & 31;
            ct[(wv * 16 + col) * 65 + ln] = (lutA[pA] + lutB[pB]) + lutC[pC];
        }
    }
    __syncthreads();

    // Scan phase: waves 0-3 only, lane = px. Op-identical to rounds 0-8.
    if (tid < 256) {
        const int px = tid;
        float u1 = 0.f, v1 = 0.f, ur = 0.f, vr = 0.f;
        unsigned slo = 0u, shi = 0u;
#pragma unroll
        for (int tc = 0; tc < TT; tc += 8) {
            float c8[8];
#pragma unroll
            for (int j = 0; j < 8; j++) c8[j] = ct[px * 65 + tc + j];
#pragma unroll
            for (int j = 0; j < 8; j++) {
                v1 = D1 * (v1 + u1);
                const float p = CP1 * v1;
                u1 = D1 * u1 + c8[j];
                vr = DR1 * (vr + ur);
                const float m = p + CR1 * vr;
                const bool sp = (m >= TH1);
                ur = DR1 * ur + (sp ? 1.f : 0.f);
                const unsigned bit = sp ? (1u << ((tc + j) & 31)) : 0u;
                if (tc < 32) slo |= bit;
                else         shi |= bit;
            }
        }
        tb[px] = make_uint2(slo, shi);
    }
    __syncthreads();

    // Transpose: wave wv -> y-row wv; lanes = t, one coalesced store each.
    {
        unsigned h = 0u;
#pragma unroll
        for (int x = 0; x < 16; x++) {
            const uint2 b = tb[wv * 16 + x];
            const unsigned w = (ln < 32) ? b.x : b.y;
            h |= ((w >> (ln & 31)) & 1u) << x;
        }
        s1h[((size_t)(n * HH + y0 + wv) * XH + tx) * TT + ln] =
            (unsigned short)h;
    }
}

// ---------------- KC: pack + conv2 patterns + lut3 scan2 -> float out ------
__global__ __launch_bounds__(NT, 1)
void kc_layer2(const unsigned short* __restrict__ s1h, const float* __restrict__ w2g,
               float* __restrict__ out) {
    __shared__ float          lut3[512];
    __shared__ unsigned       wrow[18 * 64];    // 18-bit window rows, lane = t
    __shared__ unsigned short ptile[256 * 66];  // 9-bit patterns [px][t]
    __shared__ uint2          tb[256];

    const int n = blockIdx.z, ty = blockIdx.y, tx = blockIdx.x;
    const int y0 = ty * 16;
    const int tid = threadIdx.x;
    const int wv = tid >> 6, ln = tid & 63;

    // lut3[e] = (l0+l1)+l2, each lk in j-order -> bitwise = rounds 5-8.
    if (tid < 512) {
        const int e = tid;
        float l0 = 0.f, l1 = 0.f, l2 = 0.f;
#pragma unroll
        for (int j = 0; j < 3; j++) {
            if ((e >> j) & 1)       l0 += w2g[j];
            if ((e >> (3 + j)) & 1) l1 += w2g[3 + j];
            if ((e >> (6 + j)) & 1) l2 += w2g[6 + j];
        }
        lut3[e] = (l0 + l1) + l2;
    }

    // Pack phase: 18 window rows split over 16 waves; 3 ushort loads each.
    for (int r = wv; r < 18; r += 16) {
        const int gy = y0 - 1 + r;
        unsigned hm = 0u, h0 = 0u, hp = 0u;
        if (gy >= 0 && gy < HH) {
            const unsigned short* rp =
                s1h + ((size_t)(n * HH + gy) * XH) * TT + ln;
            if (tx > 0)      hm = rp[(size_t)(tx - 1) * TT];
            h0 = rp[(size_t)tx * TT];
            if (tx + 1 < XH) hp = rp[(size_t)(tx + 1) * TT];
        }
        wrow[r * 64 + ln] = (hm >> 15) | (h0 << 1) | ((hp & 1u) << 17);
    }
    __syncthreads();

    // Pattern phase: wave wv -> px row wv (registers only, no gathers).
    {
        unsigned w18[3];
#pragma unroll
        for (int dy = 0; dy < 3; dy++) w18[dy] = wrow[(wv + dy) * 64 + ln];
#pragma unroll
        for (int col = 0; col < 16; col++) {
            const unsigned pat = ((w18[0] >> col) & 7)
                               | (((w18[1] >> col) & 7) << 3)
                               | (((w18[2] >> col) & 7) << 6);
            ptile[(wv * 16 + col) * 66 + ln] = (unsigned short)pat;
        }
    }
    __syncthreads();

    // Scan phase: waves 0-3, lane = px, one lut3 gather per t (r8 KC).
    if (tid < 256) {
        const int px = tid;
        const unsigned* pp = (const unsigned*)(ptile + px * 66);  // 2 pats/word
        float u2 = 0.f, v2 = 0.f, ur2 = 0.f, vr2 = 0.f;
        unsigned olo = 0u, ohi = 0u;
#pragma unroll
        for (int tc = 0; tc < TT; tc += 8) {
            unsigned q[4];
#pragma unroll
            for (int k = 0; k < 4; k++) q[k] = pp[tc / 2 + k];
            float l[8];
#pragma unroll
            for (int k = 0; k < 4; k++) {
                l[2 * k + 0] = lut3[q[k] & 0x1ffu];
                l[2 * k + 1] = lut3[(q[k] >> 16) & 0x1ffu];
            }
#pragma unroll
            for (int j = 0; j < 8; j++) {
                v2 = D2 * (v2 + u2);
                const float p = CP2 * v2;
                u2 = D2 * u2 + l[j];
                vr2 = DR2 * (vr2 + ur2);
                const float m = p + CR2 * vr2;
                const bool sp = (m >= TH2);
                ur2 = DR2 * ur2 + (sp ? 1.f : 0.f);
                const unsigned bit = sp ? (1u << ((tc + j) & 31)) : 0u;
                if (tc < 32) olo |= bit;
                else         ohi |= bit;
            }
        }
        tb[px] = make_uint2(olo, ohi);
    }
    __syncthreads();

    // Epilogue: wave wv -> output row y0+wv; 16 coalesced 256B stores.
    const int sh = ln & 31;
#pragma unroll
    for (int k = 0; k < 16; k++) {
        const uint2 b = tb[wv * 16 + k];             // LDS broadcast
        const unsigned w = (ln < 32) ? b.x : b.y;
        out[((size_t)(n * HH + y0 + wv) * WW + tx * 16 + k) * TT + ln] =
            (float)((w >> sh) & 1u);
    }
}

extern "C" void kernel_launch(void* const* d_in, const int* in_sizes, int n_in,
                              void* d_out, int out_size, void* d_ws, size_t ws_size,
                              hipStream_t stream) {
    const float* in = (const float*)d_in[0];   // (4,1,192,192,64) f32 spikes
    const float* w1 = (const float*)d_in[1];   // (1,1,5,5)
    const float* w2 = (const float*)d_in[2];   // (1,1,3,3)
    float* out = (float*)d_out;                // (4,1,192,192,64) f32 spikes

    unsigned short* s1h = (unsigned short*)d_ws;   // 1.18 MB scratch

    dim3 tgrid(WW / 16, HH / 16, NIMG);            // 12 x 12 x 4 = 576 blocks
    kb_layer1<<<tgrid, NT, 0, stream>>>(in, w1, s1h);
    kc_layer2<<<tgrid, NT, 0, stream>>>(s1h, w2, out);
}

// Round 10
// 118.970 us; speedup vs baseline: 1.2474x; 1.2474x over previous
//
#include <hip/hip_runtime.h>

// SLAYER 2-layer SNN, MI355X. Round-10: fine-grained fused blocks.
// Confirmed lessons: (r6) conv kernels at 2304 blocks hide LDS/L2 latency via
// block-level TLP; (r7) intermediates must stay bit-packed (f32 round-trips
// cost ~20us); (r9) never read raw float input in a low-block-count kernel,
// never build 80KB/1-block-per-CU mega-blocks.
//   KA: floats -> bitT[y][xw][t]  (1152 blocks, streaming, proven)
//   L1: per-block 4 output rows x 16 cols: window regs from global bitT ->
//       conv1 (2-row LUTs) -> ct LDS (16.6KB) -> scan1 (1 wave) -> s1h
//   L2: same structure: 3 halfwords -> 9-bit patterns -> ptile LDS -> scan2
//       (lut3[512], 1 gather/px.t) -> transpose -> coalesced float out
// All sum associations identical to rounds 0-9 (absmax == 0 every round).

#define HH   192
#define WW   192
#define NIMG 4
#define TT   64
#define NT   256
#define XW   6     // uint32 x-words per image row
#define XH   12    // 16-bit x-halfwords per image row

#define E_D 2.718281828459045
static constexpr float D1  = (float)0.36787944117144233;   // exp(-1/1)
static constexpr float CP1 = (float)(E_D);
static constexpr float DR1 = (float)0.36787944117144233;
static constexpr float CR1 = (float)(-30.0 * E_D);
static constexpr float D2  = (float)0.6065306597126334;    // exp(-1/2)
static constexpr float CP2 = (float)(E_D * 0.5);
static constexpr float DR2 = (float)0.6065306597126334;
static constexpr float CR2 = (float)(-50.0 * E_D * 0.5);
static constexpr float TH1 = 30.0f;
static constexpr float TH2 = 50.0f;

// ---------------- KA: float spikes -> x-transposed bit words ---------------
__global__ __launch_bounds__(NT)
void ka_pack(const float* __restrict__ in, unsigned* __restrict__ bitT) {
    const int gw = blockIdx.x * (NT / 64) + (threadIdx.x >> 6);
    const int ln = threadIdx.x & 63;
    const int xw = gw % XW;
    const int ny = gw / XW;                 // n*HH + y
    const float* src = in + ((size_t)ny * WW + xw * 32) * TT + ln;
    unsigned w = 0u;
#pragma unroll
    for (int x = 0; x < 32; x++) {
        const float v = src[(size_t)x * TT];
        w |= (v != 0.f) ? (1u << x) : 0u;
    }
    bitT[((size_t)ny * XW + xw) * TT + ln] = w;
}

// ---------------- L1: conv1 (2-row LUTs) + scan1 -> s1h --------------------
// Block: 4 output rows x 16 cols (64 px). Grid 12 x 48 x 4 = 2304 blocks.
__global__ __launch_bounds__(NT, 4)
void l1_convscan(const unsigned* __restrict__ bitT, const float* __restrict__ w1g,
                 unsigned short* __restrict__ s1h) {
    __shared__ float lutA[1024];          // rows 0+1: l0(p&31)+l1(p>>5)
    __shared__ float lutB[1024];          // rows 2+3
    __shared__ float lutC[32];            // row 4
    __shared__ float ct[64 * 65];         // conv out [px][t], stride 65
    __shared__ uint2 tb[64];

    const int n = blockIdx.z, ys = blockIdx.y, xs = blockIdx.x;
    const int y0 = ys * 4, x0 = xs * 16;
    const int tid = threadIdx.x;
    const int wv = tid >> 6, ln = tid & 63;

    // LUT build: 4 entries/thread; per-accumulator j-ascending == r8/r9.
#pragma unroll
    for (int e = tid; e < 1024; e += NT) {
        float l0 = 0.f, l1 = 0.f, l2 = 0.f, l3 = 0.f;
#pragma unroll
        for (int j = 0; j < 5; j++) {
            if ((e >> j) & 1)       { l0 += w1g[j];     l2 += w1g[10 + j]; }
            if ((e >> (5 + j)) & 1) { l1 += w1g[5 + j]; l3 += w1g[15 + j]; }
        }
        lutA[e] = l0 + l1;
        lutB[e] = l2 + l3;
    }
    if (tid < 32) {
        float s = 0.f;
#pragma unroll
        for (int j = 0; j < 5; j++)
            if ((tid >> j) & 1) s += w1g[20 + j];
        lutC[tid] = s;
    }

    // Window regs from global bitT (L2-resident): wave wv -> output row y0+wv.
    // w20[dy] bits c=0..19 <-> gx = x0-2+c, lane = t. Shift s in {30,14}.
    const int a = (x0 - 2) >> 5;
    const int s = (x0 - 2) & 31;
    const int gyb = y0 + wv;
    unsigned w20[5];
#pragma unroll
    for (int dy = 0; dy < 5; dy++) {
        const int gy = gyb - 2 + dy;
        unsigned wa = 0u, wb = 0u;
        if (gy >= 0 && gy < HH) {
            const unsigned* rp = bitT + ((size_t)(n * HH + gy) * XW) * TT + ln;
            if (a >= 0)     wa = rp[(size_t)a * TT];
            if (a + 1 < XW) wb = rp[(size_t)(a + 1) * TT];
        }
        w20[dy] = (wa >> s) | (wb << (32 - s));
    }
    __syncthreads();

    // Conv: lanes = t; px = wv*16 + col.
#pragma unroll
    for (int col = 0; col < 16; col++) {
        const unsigned pA = ((w20[0] >> col) & 31) | (((w20[1] >> col) & 31) << 5);
        const unsigned pB = ((w20[2] >> col) & 31) | (((w20[3] >> col) & 31) << 5);
        const unsigned pC = (w20[4] >> col) & 31;
        ct[(wv * 16 + col) * 65 + ln] = (lutA[pA] + lutB[pB]) + lutC[pC];
    }
    __syncthreads();

    // Scan: 1 wave, lane = px (64 px). Op-identical to rounds 0-9.
    if (tid < 64) {
        const int px = tid;
        float u1 = 0.f, v1 = 0.f, ur = 0.f, vr = 0.f;
        unsigned slo = 0u, shi = 0u;
#pragma unroll
        for (int tc = 0; tc < TT; tc += 8) {
            float c8[8];
#pragma unroll
            for (int j = 0; j < 8; j++) c8[j] = ct[px * 65 + tc + j];
#pragma unroll
            for (int j = 0; j < 8; j++) {
                v1 = D1 * (v1 + u1);
                const float p = CP1 * v1;
                u1 = D1 * u1 + c8[j];
                vr = DR1 * (vr + ur);
                const float m = p + CR1 * vr;
                const bool sp = (m >= TH1);
                ur = DR1 * ur + (sp ? 1.f : 0.f);
                const unsigned bit = sp ? (1u << ((tc + j) & 31)) : 0u;
                if (tc < 32) slo |= bit;
                else         shi |= bit;
            }
        }
        tb[px] = make_uint2(slo, shi);
    }
    __syncthreads();

    // Transpose: wave wv -> y-row y0+wv; lanes = t, one coalesced store.
    {
        unsigned h = 0u;
#pragma unroll
        for (int x = 0; x < 16; x++) {
            const uint2 b = tb[wv * 16 + x];         // LDS broadcast
            const unsigned w = (ln < 32) ? b.x : b.y;
            h |= ((w >> (ln & 31)) & 1u) << x;
        }
        s1h[((size_t)(n * HH + gyb) * XH + xs) * TT + ln] = (unsigned short)h;
    }
}

// ---------------- L2: conv2 patterns + lut3 scan2 -> float out -------------
// Block: 4 output rows x 16 cols (64 px). Grid 12 x 48 x 4 = 2304 blocks.
__global__ __launch_bounds__(NT, 4)
void l2_convscan(const unsigned short* __restrict__ s1h, const float* __restrict__ w2g,
                 float* __restrict__ out) {
    __shared__ float          lut3[512];
    __shared__ unsigned short ptile[64 * 66];   // 9-bit patterns [px][t]
    __shared__ uint2          tb[64];

    const int n = blockIdx.z, ys = blockIdx.y, xs = blockIdx.x;
    const int y0 = ys * 4;
    const int tid = threadIdx.x;
    const int wv = tid >> 6, ln = tid & 63;

    // lut3[e] = (l0+l1)+l2, each lk in j-order -> bitwise = rounds 5-9.
#pragma unroll
    for (int e = tid; e < 512; e += NT) {
        float l0 = 0.f, l1 = 0.f, l2 = 0.f;
#pragma unroll
        for (int j = 0; j < 3; j++) {
            if ((e >> j) & 1)       l0 += w2g[j];
            if ((e >> (3 + j)) & 1) l1 += w2g[3 + j];
            if ((e >> (6 + j)) & 1) l2 += w2g[6 + j];
        }
        lut3[e] = (l0 + l1) + l2;
    }

    // Window regs: wave wv -> output row y0+wv; 9 halfword loads, lane = t.
    const int gyb = y0 + wv;
    unsigned w18[3];
#pragma unroll
    for (int dy = 0; dy < 3; dy++) {
        const int gy = gyb - 1 + dy;
        unsigned hm = 0u, h0 = 0u, hp = 0u;
        if (gy >= 0 && gy < HH) {
            const unsigned short* rp = s1h + ((size_t)(n * HH + gy) * XH) * TT + ln;
            if (xs > 0)      hm = rp[(size_t)(xs - 1) * TT];
            h0 = rp[(size_t)xs * TT];
            if (xs + 1 < XH) hp = rp[(size_t)(xs + 1) * TT];
        }
        w18[dy] = (hm >> 15) | (h0 << 1) | ((hp & 1u) << 17);
    }
    __syncthreads();

    // Patterns (registers only): px = wv*16 + col.
#pragma unroll
    for (int col = 0; col < 16; col++) {
        const unsigned pat = ((w18[0] >> col) & 7)
                           | (((w18[1] >> col) & 7) << 3)
                           | (((w18[2] >> col) & 7) << 6);
        ptile[(wv * 16 + col) * 66 + ln] = (unsigned short)pat;
    }
    __syncthreads();

    // Scan: 1 wave, lane = px, one lut3 gather per t (r8/r9 KC).
    if (tid < 64) {
        const int px = tid;
        const unsigned* pp = (const unsigned*)(ptile + px * 66);  // 2 pats/word
        float u2 = 0.f, v2 = 0.f, ur2 = 0.f, vr2 = 0.f;
        unsigned olo = 0u, ohi = 0u;
#pragma unroll
        for (int tc = 0; tc < TT; tc += 8) {
            unsigned q[4];
#pragma unroll
            for (int k = 0; k < 4; k++) q[k] = pp[tc / 2 + k];
            float l[8];
#pragma unroll
            for (int k = 0; k < 4; k++) {
                l[2 * k + 0] = lut3[q[k] & 0x1ffu];
                l[2 * k + 1] = lut3[(q[k] >> 16) & 0x1ffu];
            }
#pragma unroll
            for (int j = 0; j < 8; j++) {
                v2 = D2 * (v2 + u2);
                const float p = CP2 * v2;
                u2 = D2 * u2 + l[j];
                vr2 = DR2 * (vr2 + ur2);
                const float m = p + CR2 * vr2;
                const bool sp = (m >= TH2);
                ur2 = DR2 * ur2 + (sp ? 1.f : 0.f);
                const unsigned bit = sp ? (1u << ((tc + j) & 31)) : 0u;
                if (tc < 32) olo |= bit;
                else         ohi |= bit;
            }
        }
        tb[px] = make_uint2(olo, ohi);
    }
    __syncthreads();

    // Epilogue: wave wv -> output row y0+wv; 16 coalesced 256B stores.
    const int sh = ln & 31;
#pragma unroll
    for (int k = 0; k < 16; k++) {
        const uint2 b = tb[wv * 16 + k];             // LDS broadcast
        const unsigned w = (ln < 32) ? b.x : b.y;
        out[((size_t)(n * HH + gyb) * WW + xs * 16 + k) * TT + ln] =
            (float)((w >> sh) & 1u);
    }
}

extern "C" void kernel_launch(void* const* d_in, const int* in_sizes, int n_in,
                              void* d_out, int out_size, void* d_ws, size_t ws_size,
                              hipStream_t stream) {
    const float* in = (const float*)d_in[0];   // (4,1,192,192,64) f32 spikes
    const float* w1 = (const float*)d_in[1];   // (1,1,5,5)
    const float* w2 = (const float*)d_in[2];   // (1,1,3,3)
    float* out = (float*)d_out;                // (4,1,192,192,64) f32 spikes

    char* ws = (char*)d_ws;
    unsigned*       bitT = (unsigned*)ws;                        // 1.18 MB
    unsigned short* s1h  = (unsigned short*)(ws + (2ull << 20)); // 1.18 MB

    const int ka_blocks = (NIMG * HH * XW) / (NT / 64);          // 1152
    dim3 cgrid(WW / 16, HH / 4, NIMG);                           // 12 x 48 x 4
    ka_pack    <<<ka_blocks, NT, 0, stream>>>(in, bitT);
    l1_convscan<<<cgrid, NT, 0, stream>>>(bitT, w1, s1h);
    l2_convscan<<<cgrid, NT, 0, stream>>>(s1h, w2, out);
}

// Round 11
// 114.922 us; speedup vs baseline: 1.2914x; 1.0352x over previous
//
#include <hip/hip_runtime.h>

// SLAYER 2-layer SNN, MI355X. Round-11: r10 structure, L1 conv via pure VALU.
// Evidence r2/r3/r8/r10: data-dependent LDS LUT gathers serialize (~240cyc,
// compiler won't pipeline); VALUBusy <=14% in every profile. So conv1 now
// accumulates 25 taps with bfe+cvt+fmac (issue-bound, zero LDS, no LUT build,
// one less barrier). fma(1,w,acc)=acc+w and fma(0,w,acc)=acc are exact ->
// sums keep the association ((l0+l1)+(l2+l3))+l4 of rounds 8-10, bitwise.
//   KA: floats -> bitT[y][xw][t]  (1152 blocks, streaming, proven)
//   L1: window regs from bitT -> VALU conv1 -> ct LDS -> scan1 (1 wave)
//       -> transpose -> s1h halfwords                     [2304 blocks]
//   L2: 3 halfwords -> 9-bit patterns (regs) -> ptile LDS -> scan2
//       (lut3[512], batched 1 gather/px.t) -> coalesced float out [2304 blocks]
// absmax == 0 every round so far; all scan ops unchanged.

#define HH   192
#define WW   192
#define NIMG 4
#define TT   64
#define NT   256
#define XW   6     // uint32 x-words per image row
#define XH   12    // 16-bit x-halfwords per image row

#define E_D 2.718281828459045
static constexpr float D1  = (float)0.36787944117144233;   // exp(-1/1)
static constexpr float CP1 = (float)(E_D);
static constexpr float DR1 = (float)0.36787944117144233;
static constexpr float CR1 = (float)(-30.0 * E_D);
static constexpr float D2  = (float)0.6065306597126334;    // exp(-1/2)
static constexpr float CP2 = (float)(E_D * 0.5);
static constexpr float DR2 = (float)0.6065306597126334;
static constexpr float CR2 = (float)(-50.0 * E_D * 0.5);
static constexpr float TH1 = 30.0f;
static constexpr float TH2 = 50.0f;

// ---------------- KA: float spikes -> x-transposed bit words ---------------
__global__ __launch_bounds__(NT)
void ka_pack(const float* __restrict__ in, unsigned* __restrict__ bitT) {
    const int gw = blockIdx.x * (NT / 64) + (threadIdx.x >> 6);
    const int ln = threadIdx.x & 63;
    const int xw = gw % XW;
    const int ny = gw / XW;                 // n*HH + y
    const float* src = in + ((size_t)ny * WW + xw * 32) * TT + ln;
    unsigned w = 0u;
#pragma unroll
    for (int x = 0; x < 32; x++) {
        const float v = src[(size_t)x * TT];
        w |= (v != 0.f) ? (1u << x) : 0u;
    }
    bitT[((size_t)ny * XW + xw) * TT + ln] = w;
}

// ---------------- L1: VALU conv1 + scan1 -> s1h ----------------------------
// Block: 4 output rows x 16 cols (64 px). Grid 12 x 48 x 4 = 2304 blocks.
__global__ __launch_bounds__(NT, 8)
void l1_convscan(const unsigned* __restrict__ bitT, const float* __restrict__ w1g,
                 unsigned short* __restrict__ s1h) {
    __shared__ float ct[64 * 65];         // conv out [px][t], stride 65
    __shared__ uint2 tb[64];

    const int n = blockIdx.z, ys = blockIdx.y, xs = blockIdx.x;
    const int y0 = ys * 4, x0 = xs * 16;
    const int tid = threadIdx.x;
    const int wv = tid >> 6, ln = tid & 63;

    // Weights: uniform -> scalar regs.
    float w1r[25];
#pragma unroll
    for (int k = 0; k < 25; k++) w1r[k] = w1g[k];

    // Window regs from global bitT (L2-resident): wave wv -> output row y0+wv.
    // w20[dy] bits c=0..19 <-> gx = x0-2+c, lane = t. Shift s in {30,14}.
    const int a = (x0 - 2) >> 5;
    const int s = (x0 - 2) & 31;
    const int gyb = y0 + wv;
    unsigned w20[5];
#pragma unroll
    for (int dy = 0; dy < 5; dy++) {
        const int gy = gyb - 2 + dy;
        unsigned wa = 0u, wb = 0u;
        if (gy >= 0 && gy < HH) {
            const unsigned* rp = bitT + ((size_t)(n * HH + gy) * XW) * TT + ln;
            if (a >= 0)     wa = rp[(size_t)a * TT];
            if (a + 1 < XW) wb = rp[(size_t)(a + 1) * TT];
        }
        w20[dy] = (wa >> s) | (wb << (32 - s));
    }

    // Conv: pure VALU, lanes = t; px = wv*16 + col. Per-row chains l0..l4 in
    // ascending j, combined ((l0+l1)+(l2+l3))+l4 == rounds 8-10 bitwise.
#pragma unroll
    for (int col = 0; col < 16; col++) {
        float l0 = 0.f, l1 = 0.f, l2 = 0.f, l3 = 0.f, l4 = 0.f;
#pragma unroll
        for (int j = 0; j < 5; j++) {
            l0 += (float)((w20[0] >> (col + j)) & 1u) * w1r[j];
            l1 += (float)((w20[1] >> (col + j)) & 1u) * w1r[5 + j];
            l2 += (float)((w20[2] >> (col + j)) & 1u) * w1r[10 + j];
            l3 += (float)((w20[3] >> (col + j)) & 1u) * w1r[15 + j];
            l4 += (float)((w20[4] >> (col + j)) & 1u) * w1r[20 + j];
        }
        ct[(wv * 16 + col) * 65 + ln] = ((l0 + l1) + (l2 + l3)) + l4;
    }
    __syncthreads();

    // Scan: 1 wave, lane = px (64 px). Op-identical to rounds 0-10.
    if (tid < 64) {
        const int px = tid;
        float u1 = 0.f, v1 = 0.f, ur = 0.f, vr = 0.f;
        unsigned slo = 0u, shi = 0u;
#pragma unroll
        for (int tc = 0; tc < TT; tc += 8) {
            float c8[8];
#pragma unroll
            for (int j = 0; j < 8; j++) c8[j] = ct[px * 65 + tc + j];
#pragma unroll
            for (int j = 0; j < 8; j++) {
                v1 = D1 * (v1 + u1);
                const float p = CP1 * v1;
                u1 = D1 * u1 + c8[j];
                vr = DR1 * (vr + ur);
                const float m = p + CR1 * vr;
                const bool sp = (m >= TH1);
                ur = DR1 * ur + (sp ? 1.f : 0.f);
                const unsigned bit = sp ? (1u << ((tc + j) & 31)) : 0u;
                if (tc < 32) slo |= bit;
                else         shi |= bit;
            }
        }
        tb[px] = make_uint2(slo, shi);
    }
    __syncthreads();

    // Transpose: wave wv -> y-row y0+wv; lanes = t, one coalesced store.
    {
        unsigned h = 0u;
#pragma unroll
        for (int x = 0; x < 16; x++) {
            const uint2 b = tb[wv * 16 + x];         // LDS broadcast
            const unsigned w = (ln < 32) ? b.x : b.y;
            h |= ((w >> (ln & 31)) & 1u) << x;
        }
        s1h[((size_t)(n * HH + gyb) * XH + xs) * TT + ln] = (unsigned short)h;
    }
}

// ---------------- L2: conv2 patterns + lut3 scan2 -> float out -------------
// Block: 4 output rows x 16 cols (64 px). Grid 12 x 48 x 4 = 2304 blocks.
__global__ __launch_bounds__(NT, 8)
void l2_convscan(const unsigned short* __restrict__ s1h, const float* __restrict__ w2g,
                 float* __restrict__ out) {
    __shared__ float          lut3[512];
    __shared__ unsigned short ptile[64 * 66];   // 9-bit patterns [px][t]
    __shared__ uint2          tb[64];

    const int n = blockIdx.z, ys = blockIdx.y, xs = blockIdx.x;
    const int y0 = ys * 4;
    const int tid = threadIdx.x;
    const int wv = tid >> 6, ln = tid & 63;

    // lut3[e] = (l0+l1)+l2, each lk in j-order -> bitwise = rounds 5-10.
#pragma unroll
    for (int e = tid; e < 512; e += NT) {
        float l0 = 0.f, l1 = 0.f, l2 = 0.f;
#pragma unroll
        for (int j = 0; j < 3; j++) {
            if ((e >> j) & 1)       l0 += w2g[j];
            if ((e >> (3 + j)) & 1) l1 += w2g[3 + j];
            if ((e >> (6 + j)) & 1) l2 += w2g[6 + j];
        }
        lut3[e] = (l0 + l1) + l2;
    }

    // Window regs: wave wv -> output row y0+wv; 9 halfword loads, lane = t.
    const int gyb = y0 + wv;
    unsigned w18[3];
#pragma unroll
    for (int dy = 0; dy < 3; dy++) {
        const int gy = gyb - 1 + dy;
        unsigned hm = 0u, h0 = 0u, hp = 0u;
        if (gy >= 0 && gy < HH) {
            const unsigned short* rp = s1h + ((size_t)(n * HH + gy) * XH) * TT + ln;
            if (xs > 0)      hm = rp[(size_t)(xs - 1) * TT];
            h0 = rp[(size_t)xs * TT];
            if (xs + 1 < XH) hp = rp[(size_t)(xs + 1) * TT];
        }
        w18[dy] = (hm >> 15) | (h0 << 1) | ((hp & 1u) << 17);
    }
    __syncthreads();

    // Patterns (registers only): px = wv*16 + col.
#pragma unroll
    for (int col = 0; col < 16; col++) {
        const unsigned pat = ((w18[0] >> col) & 7)
                           | (((w18[1] >> col) & 7) << 3)
                           | (((w18[2] >> col) & 7) << 6);
        ptile[(wv * 16 + col) * 66 + ln] = (unsigned short)pat;
    }
    __syncthreads();

    // Scan: 1 wave, lane = px, one batched lut3 gather per t (r8-r10).
    if (tid < 64) {
        const int px = tid;
        const unsigned* pp = (const unsigned*)(ptile + px * 66);  // 2 pats/word
        float u2 = 0.f, v2 = 0.f, ur2 = 0.f, vr2 = 0.f;
        unsigned olo = 0u, ohi = 0u;
#pragma unroll
        for (int tc = 0; tc < TT; tc += 8) {
            unsigned q[4];
#pragma unroll
            for (int k = 0; k < 4; k++) q[k] = pp[tc / 2 + k];
            float l[8];
#pragma unroll
            for (int k = 0; k < 4; k++) {
                l[2 * k + 0] = lut3[q[k] & 0x1ffu];
                l[2 * k + 1] = lut3[(q[k] >> 16) & 0x1ffu];
            }
#pragma unroll
            for (int j = 0; j < 8; j++) {
                v2 = D2 * (v2 + u2);
                const float p = CP2 * v2;
                u2 = D2 * u2 + l[j];
                vr2 = DR2 * (vr2 + ur2);
                const float m = p + CR2 * vr2;
                const bool sp = (m >= TH2);
                ur2 = DR2 * ur2 + (sp ? 1.f : 0.f);
                const unsigned bit = sp ? (1u << ((tc + j) & 31)) : 0u;
                if (tc < 32) olo |= bit;
                else         ohi |= bit;
            }
        }
        tb[px] = make_uint2(olo, ohi);
    }
    __syncthreads();

    // Epilogue: wave wv -> output row y0+wv; 16 coalesced 256B stores.
    const int sh = ln & 31;
#pragma unroll
    for (int k = 0; k < 16; k++) {
        const uint2 b = tb[wv * 16 + k];             // LDS broadcast
        const unsigned w = (ln < 32) ? b.x : b.y;
        out[((size_t)(n * HH + gyb) * WW + xs * 16 + k) * TT + ln] =
            (float)((w >> sh) & 1u);
    }
}

extern "C" void kernel_launch(void* const* d_in, const int* in_sizes, int n_in,
                              void* d_out, int out_size, void* d_ws, size_t ws_size,
                              hipStream_t stream) {
    const float* in = (const float*)d_in[0];   // (4,1,192,192,64) f32 spikes
    const float* w1 = (const float*)d_in[1];   // (1,1,5,5)
    const float* w2 = (const float*)d_in[2];   // (1,1,3,3)
    float* out = (float*)d_out;                // (4,1,192,192,64) f32 spikes

    char* ws = (char*)d_ws;
    unsigned*       bitT = (unsigned*)ws;                        // 1.18 MB
    unsigned short* s1h  = (unsigned short*)(ws + (2ull << 20)); // 1.18 MB

    const int ka_blocks = (NIMG * HH * XW) / (NT / 64);          // 1152
    dim3 cgrid(WW / 16, HH / 4, NIMG);                           // 12 x 48 x 4
    ka_pack    <<<ka_blocks, NT, 0, stream>>>(in, bitT);
    l1_convscan<<<cgrid, NT, 0, stream>>>(bitT, w1, s1h);
    l2_convscan<<<cgrid, NT, 0, stream>>>(s1h, w2, out);
}